// Round 1
// baseline (1492.088 us; speedup 1.0000x reference)
//
#include <hip/hip_runtime.h>

#define PROP_ALPHA 0.1f
#define PROP_KSTEPS 10

// ---------------- CSR build ----------------

__global__ void hist_kernel(const int* __restrict__ dst, int* __restrict__ degI, int E) {
    int e = blockIdx.x * blockDim.x + threadIdx.x;
    if (e < E) atomicAdd(&degI[dst[e]], 1);
}

__global__ void dinv_kernel(const int* __restrict__ degI, float* __restrict__ dinv, int N) {
    int i = blockIdx.x * blockDim.x + threadIdx.x;
    if (i < N) {
        // reference: deg = in-degree + 1 (self loop); deg >= 1 always
        float d = (float)(degI[i] + 1);
        dinv[i] = rsqrtf(d);
    }
}

// single-block exclusive scan of degI[0..N) -> rowptr[0..N]
__global__ __launch_bounds__(1024) void scan_kernel(const int* __restrict__ degI,
                                                    int* __restrict__ rowptr, int N) {
    __shared__ int s[1024];
    int t = threadIdx.x;
    int base = 0;
    if (t == 0) rowptr[0] = 0;
    int nChunks = (N + 1023) >> 10;
    for (int c = 0; c < nChunks; ++c) {
        int idx = (c << 10) + t;
        int v = (idx < N) ? degI[idx] : 0;
        s[t] = v;
        __syncthreads();
        for (int off = 1; off < 1024; off <<= 1) {
            int x = (t >= off) ? s[t - off] : 0;
            __syncthreads();
            s[t] += x;
            __syncthreads();
        }
        if (idx < N) rowptr[idx + 1] = base + s[t];
        base += s[1023];
        __syncthreads();
    }
}

__global__ void scatter_kernel(const int* __restrict__ src, const int* __restrict__ dst,
                               const int* __restrict__ rowptr, int* __restrict__ rowctr,
                               const float* __restrict__ dinv,
                               int* __restrict__ colidx, float* __restrict__ normv, int E) {
    int e = blockIdx.x * blockDim.x + threadIdx.x;
    if (e < E) {
        int d = dst[e], s = src[e];
        int p = rowptr[d] + atomicAdd(&rowctr[d], 1);
        colidx[p] = s;
        normv[p] = dinv[s] * dinv[d];
    }
}

// ---------------- dense layers ----------------

// h1[N,128] = x[N,64] @ W3[64,128] + b3
__global__ __launch_bounds__(128) void gemm1_kernel(const float* __restrict__ x,
                                                    const float* __restrict__ W,
                                                    const float* __restrict__ b,
                                                    float* __restrict__ out, int N) {
    __shared__ float Ws[64 * 128];
    __shared__ float xs[32 * 64];
    int t = threadIdx.x;
    #pragma unroll
    for (int i = 0; i < 64; ++i) Ws[i * 128 + t] = W[i * 128 + t];
    float bc = b[t];
    int r0 = blockIdx.x * 32;
    int rows = min(32, N - r0);
    for (int i = t; i < rows * 64; i += 128) xs[i] = x[r0 * 64 + i];
    __syncthreads();
    for (int r = 0; r < rows; ++r) {
        float acc = bc;
        #pragma unroll
        for (int k = 0; k < 64; ++k) acc += xs[r * 64 + k] * Ws[k * 128 + t];
        out[(size_t)(r0 + r) * 128 + t] = acc;
    }
}

// h2[N,64] = relu(z[N,128]) @ W4[128,64] + b4
__global__ __launch_bounds__(256) void gemm2_kernel(const float* __restrict__ z,
                                                    const float* __restrict__ W,
                                                    const float* __restrict__ b,
                                                    float* __restrict__ out, int N) {
    __shared__ float Ws[128 * 64];
    __shared__ float zs[32 * 128];
    int t = threadIdx.x;
    for (int i = t; i < 128 * 64; i += 256) Ws[i] = W[i];
    int col = t & 63, rg = t >> 6;
    float bc = b[col];
    int r0 = blockIdx.x * 32;
    int rows = min(32, N - r0);
    for (int i = t; i < rows * 128; i += 256) zs[i] = fmaxf(z[(size_t)r0 * 128 + i], 0.0f);
    __syncthreads();
    for (int r = rg; r < rows; r += 4) {
        float acc = bc;
        #pragma unroll
        for (int k = 0; k < 128; ++k) acc += zs[r * 128 + k] * Ws[k * 64 + col];
        out[(size_t)(r0 + r) * 64 + col] = acc;
    }
}

// ---------------- propagation ----------------

// one wave per node, C=128 via float2 per lane
__global__ __launch_bounds__(256) void prop128_kernel(const float* __restrict__ zin,
                                                      const float* __restrict__ h,
                                                      const int* __restrict__ rowptr,
                                                      const int* __restrict__ colidx,
                                                      const float* __restrict__ normv,
                                                      const float* __restrict__ dinv,
                                                      float* __restrict__ zout, int N) {
    int wave = threadIdx.x >> 6;
    int lane = threadIdx.x & 63;
    int i = blockIdx.x * 4 + wave;
    if (i >= N) return;
    i = __builtin_amdgcn_readfirstlane(i);   // wave-uniform -> scalar loads below
    int beg = rowptr[i], end = rowptr[i + 1];
    const float2* zin2 = (const float2*)zin;
    float di = dinv[i];
    float w0 = di * di;
    float2 zi = zin2[(size_t)i * 64 + lane];
    float2 acc;
    acc.x = w0 * zi.x;
    acc.y = w0 * zi.y;
    for (int e = beg; e < end; ++e) {
        int s = colidx[e];
        float w = normv[e];
        float2 v = zin2[(size_t)s * 64 + lane];
        acc.x += w * v.x;
        acc.y += w * v.y;
    }
    float2 hv = ((const float2*)h)[(size_t)i * 64 + lane];
    float2 o;
    o.x = (1.0f - PROP_ALPHA) * acc.x + PROP_ALPHA * hv.x;
    o.y = (1.0f - PROP_ALPHA) * acc.y + PROP_ALPHA * hv.y;
    ((float2*)zout)[(size_t)i * 64 + lane] = o;
}

// one wave per node, C=64, one float per lane
__global__ __launch_bounds__(256) void prop64_kernel(const float* __restrict__ zin,
                                                     const float* __restrict__ h,
                                                     const int* __restrict__ rowptr,
                                                     const int* __restrict__ colidx,
                                                     const float* __restrict__ normv,
                                                     const float* __restrict__ dinv,
                                                     float* __restrict__ zout, int N) {
    int wave = threadIdx.x >> 6;
    int lane = threadIdx.x & 63;
    int i = blockIdx.x * 4 + wave;
    if (i >= N) return;
    i = __builtin_amdgcn_readfirstlane(i);
    int beg = rowptr[i], end = rowptr[i + 1];
    float di = dinv[i];
    float acc = di * di * zin[(size_t)i * 64 + lane];
    for (int e = beg; e < end; ++e) {
        int s = colidx[e];
        float w = normv[e];
        acc += w * zin[(size_t)s * 64 + lane];
    }
    float hv = h[(size_t)i * 64 + lane];
    zout[(size_t)i * 64 + lane] = (1.0f - PROP_ALPHA) * acc + PROP_ALPHA * hv;
}

// ---------------- launch ----------------

extern "C" void kernel_launch(void* const* d_in, const int* in_sizes, int n_in,
                              void* d_out, int out_size, void* d_ws, size_t ws_size,
                              hipStream_t stream) {
    const float* x  = (const float*)d_in[0];
    const int*   ei = (const int*)d_in[1];
    const float* W3 = (const float*)d_in[2];
    const float* b3 = (const float*)d_in[3];
    const float* W4 = (const float*)d_in[4];
    const float* b4 = (const float*)d_in[5];
    float* out = (float*)d_out;

    int N = in_sizes[0] / 64;   // IN_CH = 64
    int E = in_sizes[1] / 2;
    const int* srcA = ei;
    const int* dstA = ei + E;

    char* ws = (char*)d_ws;
    size_t off = 0;
    auto alloc = [&](size_t bytes) -> void* {
        void* p = ws + off;
        off = (off + bytes + 255) & ~(size_t)255;
        return p;
    };

    int*   degI   = (int*)alloc((size_t)N * 4);
    int*   rowptr = (int*)alloc(((size_t)N + 1) * 4);
    int*   rowctr = (int*)alloc((size_t)N * 4);
    float* dinv   = (float*)alloc((size_t)N * 4);
    int*   colidx = (int*)alloc((size_t)E * 4);
    float* normv  = (float*)alloc((size_t)E * 4);
    float* h1     = (float*)alloc((size_t)N * 128 * 4);  // later reused as h2 (N*64)
    float* zA     = (float*)alloc((size_t)N * 128 * 4);
    float* zB     = (float*)alloc((size_t)N * 128 * 4);

    hipMemsetAsync(degI, 0, (size_t)N * 4, stream);
    hipMemsetAsync(rowctr, 0, (size_t)N * 4, stream);

    // --- CSR build ---
    hist_kernel<<<(E + 255) / 256, 256, 0, stream>>>(dstA, degI, E);
    dinv_kernel<<<(N + 255) / 256, 256, 0, stream>>>(degI, dinv, N);
    scan_kernel<<<1, 1024, 0, stream>>>(degI, rowptr, N);
    scatter_kernel<<<(E + 255) / 256, 256, 0, stream>>>(srcA, dstA, rowptr, rowctr,
                                                        dinv, colidx, normv, E);

    // --- h1 = x @ W3 + b3 ---
    gemm1_kernel<<<(N + 31) / 32, 128, 0, stream>>>(x, W3, b3, h1, N);

    // --- prop1: K steps on C=128, ping-pong zA/zB, step0 reads h1 ---
    int propGrid = (N + 3) / 4;
    for (int s = 0; s < PROP_KSTEPS; ++s) {
        const float* in  = (s == 0) ? h1 : ((s & 1) ? zA : zB);
        float*       o   = (s & 1) ? zB : zA;
        prop128_kernel<<<propGrid, 256, 0, stream>>>(in, h1, rowptr, colidx, normv,
                                                     dinv, o, N);
    }
    // final z1 is in zB (step 9 writes zB)

    // --- h2 = relu(z1) @ W4 + b4, stored into h1's buffer (h1 is dead) ---
    float* h2 = h1;
    gemm2_kernel<<<(N + 31) / 32, 256, 0, stream>>>(zB, W4, b4, h2, N);

    // --- prop2: K steps on C=64, ping-pong zA / d_out, step 9 lands in d_out ---
    for (int s = 0; s < PROP_KSTEPS; ++s) {
        const float* in = (s == 0) ? h2 : ((s & 1) ? zA : out);
        float*       o  = (s & 1) ? out : zA;
        prop64_kernel<<<propGrid, 256, 0, stream>>>(in, h2, rowptr, colidx, normv,
                                                    dinv, o, N);
    }
}

// Round 2
// 1141.975 us; speedup vs baseline: 1.3066x; 1.3066x over previous
//
#include <hip/hip_runtime.h>

#define PROP_ALPHA 0.1f
#define PROP_KSTEPS 10

// ---------------- CSR build ----------------

__global__ void hist_kernel(const int* __restrict__ dst, int* __restrict__ degI, int E) {
    int e = blockIdx.x * blockDim.x + threadIdx.x;
    if (e < E) atomicAdd(&degI[dst[e]], 1);
}

__global__ void dinv_kernel(const int* __restrict__ degI, float* __restrict__ dinv, int N) {
    int i = blockIdx.x * blockDim.x + threadIdx.x;
    if (i < N) {
        float d = (float)(degI[i] + 1);   // + self loop
        dinv[i] = rsqrtf(d);
    }
}

// ---- 3-kernel device-wide exclusive scan (N <= 256*256) ----

__global__ __launch_bounds__(256) void scan1_kernel(const int* __restrict__ degI,
                                                    int* __restrict__ rowptr,
                                                    int* __restrict__ blockSums, int N) {
    __shared__ int s[256];
    int t = threadIdx.x;
    int idx = blockIdx.x * 256 + t;
    s[t] = (idx < N) ? degI[idx] : 0;
    __syncthreads();
    for (int off = 1; off < 256; off <<= 1) {
        int x = (t >= off) ? s[t - off] : 0;
        __syncthreads();
        s[t] += x;
        __syncthreads();
    }
    if (idx < N) rowptr[idx + 1] = s[t];           // block-local inclusive
    if (t == 255) blockSums[blockIdx.x] = s[255];
    if (blockIdx.x == 0 && t == 0) rowptr[0] = 0;
}

__global__ __launch_bounds__(256) void scan2_kernel(int* __restrict__ blockSums, int nB) {
    __shared__ int s[256];
    int t = threadIdx.x;
    s[t] = (t < nB) ? blockSums[t] : 0;
    __syncthreads();
    for (int off = 1; off < 256; off <<= 1) {
        int x = (t >= off) ? s[t - off] : 0;
        __syncthreads();
        s[t] += x;
        __syncthreads();
    }
    if (t < nB) blockSums[t] = (t == 0) ? 0 : s[t - 1];   // exclusive
}

__global__ void scan3_kernel(int* __restrict__ rowptr, const int* __restrict__ blockSums,
                             int N) {
    int idx = blockIdx.x * 256 + threadIdx.x;
    if (idx < N) rowptr[idx + 1] += blockSums[blockIdx.x];
}

__global__ void scatter_kernel(const int* __restrict__ src, const int* __restrict__ dst,
                               const int* __restrict__ rowptr, int* __restrict__ rowctr,
                               const float* __restrict__ dinv,
                               int* __restrict__ colidx, float* __restrict__ normv, int E) {
    int e = blockIdx.x * blockDim.x + threadIdx.x;
    if (e < E) {
        int d = dst[e], s = src[e];
        int p = rowptr[d] + atomicAdd(&rowctr[d], 1);
        colidx[p] = s;
        normv[p] = dinv[s] * dinv[d];
    }
}

// ---------------- dense layers ----------------

__global__ __launch_bounds__(128) void gemm1_kernel(const float* __restrict__ x,
                                                    const float* __restrict__ W,
                                                    const float* __restrict__ b,
                                                    float* __restrict__ out, int N) {
    __shared__ float Ws[64 * 128];
    __shared__ float xs[32 * 64];
    int t = threadIdx.x;
    #pragma unroll
    for (int i = 0; i < 64; ++i) Ws[i * 128 + t] = W[i * 128 + t];
    float bc = b[t];
    int r0 = blockIdx.x * 32;
    int rows = min(32, N - r0);
    for (int i = t; i < rows * 64; i += 128) xs[i] = x[r0 * 64 + i];
    __syncthreads();
    for (int r = 0; r < rows; ++r) {
        float acc = bc;
        #pragma unroll
        for (int k = 0; k < 64; ++k) acc += xs[r * 64 + k] * Ws[k * 128 + t];
        out[(size_t)(r0 + r) * 128 + t] = acc;
    }
}

__global__ __launch_bounds__(256) void gemm2_kernel(const float* __restrict__ z,
                                                    const float* __restrict__ W,
                                                    const float* __restrict__ b,
                                                    float* __restrict__ out, int N) {
    __shared__ float Ws[128 * 64];
    __shared__ float zs[32 * 128];
    int t = threadIdx.x;
    for (int i = t; i < 128 * 64; i += 256) Ws[i] = W[i];
    int col = t & 63, rg = t >> 6;
    float bc = b[col];
    int r0 = blockIdx.x * 32;
    int rows = min(32, N - r0);
    for (int i = t; i < rows * 128; i += 256) zs[i] = fmaxf(z[(size_t)r0 * 128 + i], 0.0f);
    __syncthreads();
    for (int r = rg; r < rows; r += 4) {
        float acc = bc;
        #pragma unroll
        for (int k = 0; k < 128; ++k) acc += zs[r * 128 + k] * Ws[k * 64 + col];
        out[(size_t)(r0 + r) * 64 + col] = acc;
    }
}

// ---------------- propagation ----------------

// one wave per node, C=128 via float2 per lane; edge loop unrolled x4 for MLP
__global__ __launch_bounds__(256) void prop128_kernel(const float* __restrict__ zin,
                                                      const float* __restrict__ h,
                                                      const int* __restrict__ rowptr,
                                                      const int* __restrict__ colidx,
                                                      const float* __restrict__ normv,
                                                      const float* __restrict__ dinv,
                                                      float* __restrict__ zout, int N) {
    int wave = threadIdx.x >> 6;
    int lane = threadIdx.x & 63;
    int i = blockIdx.x * 4 + wave;
    if (i >= N) return;
    i = __builtin_amdgcn_readfirstlane(i);   // wave-uniform -> scalar CSR loads
    int beg = rowptr[i], end = rowptr[i + 1];
    const float2* zin2 = (const float2*)zin;
    float di = dinv[i];
    float w0 = di * di;
    size_t li = (size_t)i * 64 + lane;
    float2 zi = zin2[li];
    float2 accA = {w0 * zi.x, w0 * zi.y};
    float2 accB = {0.0f, 0.0f};
    int e = beg;
    for (; e + 4 <= end; e += 4) {
        int s0 = colidx[e], s1 = colidx[e + 1], s2 = colidx[e + 2], s3 = colidx[e + 3];
        float n0 = normv[e], n1 = normv[e + 1], n2 = normv[e + 2], n3 = normv[e + 3];
        float2 v0 = zin2[(size_t)s0 * 64 + lane];
        float2 v1 = zin2[(size_t)s1 * 64 + lane];
        float2 v2 = zin2[(size_t)s2 * 64 + lane];
        float2 v3 = zin2[(size_t)s3 * 64 + lane];
        accA.x += n0 * v0.x; accA.y += n0 * v0.y;
        accB.x += n1 * v1.x; accB.y += n1 * v1.y;
        accA.x += n2 * v2.x; accA.y += n2 * v2.y;
        accB.x += n3 * v3.x; accB.y += n3 * v3.y;
    }
    for (; e < end; ++e) {
        int s = colidx[e];
        float w = normv[e];
        float2 v = zin2[(size_t)s * 64 + lane];
        accA.x += w * v.x; accA.y += w * v.y;
    }
    accA.x += accB.x; accA.y += accB.y;
    float2 hv = ((const float2*)h)[li];
    float2 o;
    o.x = (1.0f - PROP_ALPHA) * accA.x + PROP_ALPHA * hv.x;
    o.y = (1.0f - PROP_ALPHA) * accA.y + PROP_ALPHA * hv.y;
    ((float2*)zout)[li] = o;
}

// one wave per node, C=64, one float per lane; edge loop unrolled x4
__global__ __launch_bounds__(256) void prop64_kernel(const float* __restrict__ zin,
                                                     const float* __restrict__ h,
                                                     const int* __restrict__ rowptr,
                                                     const int* __restrict__ colidx,
                                                     const float* __restrict__ normv,
                                                     const float* __restrict__ dinv,
                                                     float* __restrict__ zout, int N) {
    int wave = threadIdx.x >> 6;
    int lane = threadIdx.x & 63;
    int i = blockIdx.x * 4 + wave;
    if (i >= N) return;
    i = __builtin_amdgcn_readfirstlane(i);
    int beg = rowptr[i], end = rowptr[i + 1];
    float di = dinv[i];
    size_t li = (size_t)i * 64 + lane;
    float accA = di * di * zin[li];
    float accB = 0.0f;
    int e = beg;
    for (; e + 4 <= end; e += 4) {
        int s0 = colidx[e], s1 = colidx[e + 1], s2 = colidx[e + 2], s3 = colidx[e + 3];
        float n0 = normv[e], n1 = normv[e + 1], n2 = normv[e + 2], n3 = normv[e + 3];
        float v0 = zin[(size_t)s0 * 64 + lane];
        float v1 = zin[(size_t)s1 * 64 + lane];
        float v2 = zin[(size_t)s2 * 64 + lane];
        float v3 = zin[(size_t)s3 * 64 + lane];
        accA += n0 * v0;
        accB += n1 * v1;
        accA += n2 * v2;
        accB += n3 * v3;
    }
    for (; e < end; ++e) {
        accA += normv[e] * zin[(size_t)colidx[e] * 64 + lane];
    }
    accA += accB;
    float hv = h[li];
    zout[li] = (1.0f - PROP_ALPHA) * accA + PROP_ALPHA * hv;
}

// ---------------- launch ----------------

extern "C" void kernel_launch(void* const* d_in, const int* in_sizes, int n_in,
                              void* d_out, int out_size, void* d_ws, size_t ws_size,
                              hipStream_t stream) {
    const float* x  = (const float*)d_in[0];
    const int*   ei = (const int*)d_in[1];
    const float* W3 = (const float*)d_in[2];
    const float* b3 = (const float*)d_in[3];
    const float* W4 = (const float*)d_in[4];
    const float* b4 = (const float*)d_in[5];
    float* out = (float*)d_out;

    int N = in_sizes[0] / 64;   // IN_CH = 64
    int E = in_sizes[1] / 2;
    const int* srcA = ei;
    const int* dstA = ei + E;

    char* ws = (char*)d_ws;
    size_t off = 0;
    auto alloc = [&](size_t bytes) -> void* {
        void* p = ws + off;
        off = (off + bytes + 255) & ~(size_t)255;
        return p;
    };

    int nScanB = (N + 255) / 256;

    int*   degI   = (int*)alloc((size_t)N * 4);
    int*   rowptr = (int*)alloc(((size_t)N + 1) * 4);
    int*   rowctr = (int*)alloc((size_t)N * 4);
    int*   bsums  = (int*)alloc((size_t)nScanB * 4);
    float* dinv   = (float*)alloc((size_t)N * 4);
    int*   colidx = (int*)alloc((size_t)E * 4);
    float* normv  = (float*)alloc((size_t)E * 4);
    float* h1     = (float*)alloc((size_t)N * 128 * 4);  // later reused as h2 (N*64)
    float* zA     = (float*)alloc((size_t)N * 128 * 4);
    float* zB     = (float*)alloc((size_t)N * 128 * 4);

    hipMemsetAsync(degI, 0, (size_t)N * 4, stream);
    hipMemsetAsync(rowctr, 0, (size_t)N * 4, stream);

    // --- CSR build ---
    hist_kernel<<<(E + 255) / 256, 256, 0, stream>>>(dstA, degI, E);
    dinv_kernel<<<(N + 255) / 256, 256, 0, stream>>>(degI, dinv, N);
    scan1_kernel<<<nScanB, 256, 0, stream>>>(degI, rowptr, bsums, N);
    scan2_kernel<<<1, 256, 0, stream>>>(bsums, nScanB);
    scan3_kernel<<<nScanB, 256, 0, stream>>>(rowptr, bsums, N);
    scatter_kernel<<<(E + 255) / 256, 256, 0, stream>>>(srcA, dstA, rowptr, rowctr,
                                                        dinv, colidx, normv, E);

    // --- h1 = x @ W3 + b3 ---
    gemm1_kernel<<<(N + 31) / 32, 128, 0, stream>>>(x, W3, b3, h1, N);

    // --- prop1: K steps on C=128, ping-pong zA/zB, step0 reads h1 ---
    int propGrid = (N + 3) / 4;
    for (int s = 0; s < PROP_KSTEPS; ++s) {
        const float* in  = (s == 0) ? h1 : ((s & 1) ? zA : zB);
        float*       o   = (s & 1) ? zB : zA;
        prop128_kernel<<<propGrid, 256, 0, stream>>>(in, h1, rowptr, colidx, normv,
                                                     dinv, o, N);
    }
    // final z1 is in zB (step 9 writes zB)

    // --- h2 = relu(z1) @ W4 + b4, stored into h1's buffer (h1 is dead) ---
    float* h2 = h1;
    gemm2_kernel<<<(N + 31) / 32, 256, 0, stream>>>(zB, W4, b4, h2, N);

    // --- prop2: K steps on C=64, ping-pong zA / d_out, step 9 lands in d_out ---
    for (int s = 0; s < PROP_KSTEPS; ++s) {
        const float* in = (s == 0) ? h2 : ((s & 1) ? zA : out);
        float*       o  = (s & 1) ? out : zA;
        prop64_kernel<<<propGrid, 256, 0, stream>>>(in, h2, rowptr, colidx, normv,
                                                    dinv, o, N);
    }
}

// Round 3
// 997.502 us; speedup vs baseline: 1.4958x; 1.1448x over previous
//
#include <hip/hip_runtime.h>

#define PROP_ALPHA 0.1f
#define PROP_KSTEPS 10

// ---------------- CSR build ----------------

__global__ void hist_kernel(const int* __restrict__ dst, int* __restrict__ degI, int E) {
    int e = blockIdx.x * blockDim.x + threadIdx.x;
    if (e < E) atomicAdd(&degI[dst[e]], 1);
}

__global__ void dinv_kernel(const int* __restrict__ degI, float* __restrict__ dinv, int N) {
    int i = blockIdx.x * blockDim.x + threadIdx.x;
    if (i < N) {
        float d = (float)(degI[i] + 1);   // + self loop
        dinv[i] = rsqrtf(d);
    }
}

// ---- 3-kernel device-wide exclusive scan (N <= 256*256) ----

__global__ __launch_bounds__(256) void scan1_kernel(const int* __restrict__ degI,
                                                    int* __restrict__ rowptr,
                                                    int* __restrict__ blockSums, int N) {
    __shared__ int s[256];
    int t = threadIdx.x;
    int idx = blockIdx.x * 256 + t;
    s[t] = (idx < N) ? degI[idx] : 0;
    __syncthreads();
    for (int off = 1; off < 256; off <<= 1) {
        int x = (t >= off) ? s[t - off] : 0;
        __syncthreads();
        s[t] += x;
        __syncthreads();
    }
    if (idx < N) rowptr[idx + 1] = s[t];           // block-local inclusive
    if (t == 255) blockSums[blockIdx.x] = s[255];
    if (blockIdx.x == 0 && t == 0) rowptr[0] = 0;
}

__global__ __launch_bounds__(256) void scan2_kernel(int* __restrict__ blockSums, int nB) {
    __shared__ int s[256];
    int t = threadIdx.x;
    s[t] = (t < nB) ? blockSums[t] : 0;
    __syncthreads();
    for (int off = 1; off < 256; off <<= 1) {
        int x = (t >= off) ? s[t - off] : 0;
        __syncthreads();
        s[t] += x;
        __syncthreads();
    }
    if (t < nB) blockSums[t] = (t == 0) ? 0 : s[t - 1];   // exclusive
}

__global__ void scan3_kernel(int* __restrict__ rowptr, const int* __restrict__ blockSums,
                             int N) {
    int idx = blockIdx.x * 256 + threadIdx.x;
    if (idx < N) rowptr[idx + 1] += blockSums[blockIdx.x];
}

__global__ void scatter_kernel(const int* __restrict__ src, const int* __restrict__ dst,
                               const int* __restrict__ rowptr, int* __restrict__ rowctr,
                               const float* __restrict__ dinv,
                               int* __restrict__ colidx, float* __restrict__ normv, int E) {
    int e = blockIdx.x * blockDim.x + threadIdx.x;
    if (e < E) {
        int d = dst[e], s = src[e];
        int p = rowptr[d] + atomicAdd(&rowctr[d], 1);
        colidx[p] = s;
        normv[p] = dinv[s] * dinv[d];
    }
}

// ---------------- fused MLP: h2 = relu(zx@W3 + v*b3^T)@W4 + b4 ----------------

__global__ __launch_bounds__(256) void fusedmlp_kernel(const float* __restrict__ zx,
                                                       const float* __restrict__ v,
                                                       const float* __restrict__ W3,
                                                       const float* __restrict__ b3,
                                                       const float* __restrict__ W4,
                                                       const float* __restrict__ b4,
                                                       float* __restrict__ h2, int N) {
    __shared__ float Ws[128 * 64];   // 32 KB, holds W3 then W4
    __shared__ float zs[32 * 65];    // padded rows
    __shared__ float ts[32 * 128];
    __shared__ float vs[32];
    int t = threadIdx.x;
    int r0 = blockIdx.x * 32;
    int rows = min(32, N - r0);
    for (int idx = t; idx < 64 * 128; idx += 256) Ws[idx] = W3[idx];
    for (int idx = t; idx < rows * 64; idx += 256) {
        int r = idx >> 6, k = idx & 63;
        zs[r * 65 + k] = zx[(size_t)r0 * 64 + idx];
    }
    if (t < rows) vs[t] = v[r0 + t];
    __syncthreads();
    // layer 1: ts = relu(zs @ W3 + vs*b3)
    {
        int col = t & 127, rg = t >> 7;
        float bc = b3[col];
        for (int r = rg; r < rows; r += 2) {
            float acc = vs[r] * bc;
            #pragma unroll
            for (int k = 0; k < 64; ++k) acc += zs[r * 65 + k] * Ws[k * 128 + col];
            ts[r * 128 + col] = fmaxf(acc, 0.0f);
        }
    }
    __syncthreads();
    for (int idx = t; idx < 128 * 64; idx += 256) Ws[idx] = W4[idx];
    __syncthreads();
    // layer 2: h2 = ts @ W4 + b4   (b4 plain: it is propagated inside h2)
    {
        int col = t & 63, rg = t >> 6;
        float bc = b4[col];
        for (int r = rg; r < rows; r += 4) {
            float acc = bc;
            #pragma unroll
            for (int k = 0; k < 128; ++k) acc += ts[r * 128 + k] * Ws[k * 64 + col];
            h2[(size_t)(r0 + r) * 64 + col] = acc;
        }
    }
}

// ---------------- propagation ----------------

// ones-vector propagation: v_{k+1} = 0.9 * Â v_k + 0.1 * 1   (v_0 = 1)
__global__ void propvec_kernel(const float* __restrict__ vin,
                               const int* __restrict__ rowptr,
                               const int* __restrict__ colidx,
                               const float* __restrict__ normv,
                               const float* __restrict__ dinv,
                               float* __restrict__ vout, int N, int firstOnes) {
    int i = blockIdx.x * blockDim.x + threadIdx.x;
    if (i >= N) return;
    int beg = rowptr[i], end = rowptr[i + 1];
    float di = dinv[i];
    float self = firstOnes ? 1.0f : vin[i];
    float acc = di * di * self;
    for (int e = beg; e < end; ++e) {
        float vv = firstOnes ? 1.0f : vin[colidx[e]];
        acc += normv[e] * vv;
    }
    vout[i] = (1.0f - PROP_ALPHA) * acc + PROP_ALPHA;
}

// one wave per node, C=64, one float per lane; edge loop unrolled x8, 4 accumulators
__global__ __launch_bounds__(256) void prop64_kernel(const float* __restrict__ zin,
                                                     const float* __restrict__ h,
                                                     const int* __restrict__ rowptr,
                                                     const int* __restrict__ colidx,
                                                     const float* __restrict__ normv,
                                                     const float* __restrict__ dinv,
                                                     float* __restrict__ zout, int N) {
    int wave = threadIdx.x >> 6;
    int lane = threadIdx.x & 63;
    int i = blockIdx.x * 4 + wave;
    if (i >= N) return;
    i = __builtin_amdgcn_readfirstlane(i);   // wave-uniform -> scalar CSR loads
    int beg = rowptr[i], end = rowptr[i + 1];
    float di = dinv[i];
    size_t li = (size_t)i * 64 + lane;
    float acc0 = di * di * zin[li];
    float acc1 = 0.0f, acc2 = 0.0f, acc3 = 0.0f;
    int e = beg;
    for (; e + 8 <= end; e += 8) {
        int s0 = colidx[e],     s1 = colidx[e + 1], s2 = colidx[e + 2], s3 = colidx[e + 3];
        int s4 = colidx[e + 4], s5 = colidx[e + 5], s6 = colidx[e + 6], s7 = colidx[e + 7];
        float n0 = normv[e],     n1 = normv[e + 1], n2 = normv[e + 2], n3 = normv[e + 3];
        float n4 = normv[e + 4], n5 = normv[e + 5], n6 = normv[e + 6], n7 = normv[e + 7];
        float v0 = zin[(size_t)s0 * 64 + lane];
        float v1 = zin[(size_t)s1 * 64 + lane];
        float v2 = zin[(size_t)s2 * 64 + lane];
        float v3 = zin[(size_t)s3 * 64 + lane];
        float v4 = zin[(size_t)s4 * 64 + lane];
        float v5 = zin[(size_t)s5 * 64 + lane];
        float v6 = zin[(size_t)s6 * 64 + lane];
        float v7 = zin[(size_t)s7 * 64 + lane];
        acc0 += n0 * v0; acc1 += n1 * v1; acc2 += n2 * v2; acc3 += n3 * v3;
        acc0 += n4 * v4; acc1 += n5 * v5; acc2 += n6 * v6; acc3 += n7 * v7;
    }
    for (; e < end; ++e) {
        acc0 += normv[e] * zin[(size_t)colidx[e] * 64 + lane];
    }
    float acc = (acc0 + acc1) + (acc2 + acc3);
    float hv = h[li];
    zout[li] = (1.0f - PROP_ALPHA) * acc + PROP_ALPHA * hv;
}

// ---------------- launch ----------------

extern "C" void kernel_launch(void* const* d_in, const int* in_sizes, int n_in,
                              void* d_out, int out_size, void* d_ws, size_t ws_size,
                              hipStream_t stream) {
    const float* x  = (const float*)d_in[0];
    const int*   ei = (const int*)d_in[1];
    const float* W3 = (const float*)d_in[2];
    const float* b3 = (const float*)d_in[3];
    const float* W4 = (const float*)d_in[4];
    const float* b4 = (const float*)d_in[5];
    float* out = (float*)d_out;

    int N = in_sizes[0] / 64;   // IN_CH = 64
    int E = in_sizes[1] / 2;
    const int* srcA = ei;
    const int* dstA = ei + E;

    char* ws = (char*)d_ws;
    size_t off = 0;
    auto alloc = [&](size_t bytes) -> void* {
        void* p = ws + off;
        off = (off + bytes + 255) & ~(size_t)255;
        return p;
    };

    int nScanB = (N + 255) / 256;

    int*   degI   = (int*)alloc((size_t)N * 4);
    int*   rowptr = (int*)alloc(((size_t)N + 1) * 4);
    int*   rowctr = (int*)alloc((size_t)N * 4);
    int*   bsums  = (int*)alloc((size_t)nScanB * 4);
    float* dinv   = (float*)alloc((size_t)N * 4);
    int*   colidx = (int*)alloc((size_t)E * 4);
    float* normv  = (float*)alloc((size_t)E * 4);
    float* vA     = (float*)alloc((size_t)N * 4);
    float* vB     = (float*)alloc((size_t)N * 4);
    float* zA     = (float*)alloc((size_t)N * 64 * 4);
    float* zB     = (float*)alloc((size_t)N * 64 * 4);
    float* h2     = (float*)alloc((size_t)N * 64 * 4);

    hipMemsetAsync(degI, 0, (size_t)N * 4, stream);
    hipMemsetAsync(rowctr, 0, (size_t)N * 4, stream);

    // --- CSR build ---
    hist_kernel<<<(E + 255) / 256, 256, 0, stream>>>(dstA, degI, E);
    dinv_kernel<<<(N + 255) / 256, 256, 0, stream>>>(degI, dinv, N);
    scan1_kernel<<<nScanB, 256, 0, stream>>>(degI, rowptr, bsums, N);
    scan2_kernel<<<1, 256, 0, stream>>>(bsums, nScanB);
    scan3_kernel<<<nScanB, 256, 0, stream>>>(rowptr, bsums, N);
    scatter_kernel<<<(E + 255) / 256, 256, 0, stream>>>(srcA, dstA, rowptr, rowctr,
                                                        dinv, colidx, normv, E);

    // --- v = M * ones  (carries the b3 bias through prop1) ---
    for (int s = 0; s < PROP_KSTEPS; ++s) {
        const float* in = (s == 0) ? vA /*unused*/ : ((s & 1) ? vA : vB);
        float*       o  = (s & 1) ? vB : vA;
        propvec_kernel<<<nScanB, 256, 0, stream>>>(in, rowptr, colidx, normv,
                                                   dinv, o, N, s == 0 ? 1 : 0);
    }
    // final v in vB (s=9 writes vB)

    // --- zx = M * x : prop1 at C=64 instead of C=128 (linearity of prop) ---
    int propGrid = (N + 3) / 4;
    for (int s = 0; s < PROP_KSTEPS; ++s) {
        const float* in = (s == 0) ? x : ((s & 1) ? zA : zB);
        float*       o  = (s & 1) ? zB : zA;
        prop64_kernel<<<propGrid, 256, 0, stream>>>(in, x, rowptr, colidx, normv,
                                                    dinv, o, N);
    }
    // final zx in zB

    // --- h2 = relu(zx@W3 + v*b3^T)@W4 + b4 ---
    fusedmlp_kernel<<<(N + 31) / 32, 256, 0, stream>>>(zB, vB, W3, b3, W4, b4, h2, N);

    // --- prop2: K steps on C=64, ping-pong zA / d_out, step 9 lands in d_out ---
    for (int s = 0; s < PROP_KSTEPS; ++s) {
        const float* in = (s == 0) ? h2 : ((s & 1) ? zA : out);
        float*       o  = (s & 1) ? out : zA;
        prop64_kernel<<<propGrid, 256, 0, stream>>>(in, h2, rowptr, colidx, normv,
                                                    dinv, o, N);
    }
}